// Round 1
// baseline (276.686 us; speedup 1.0000x reference)
//
#include <hip/hip_runtime.h>
#include <hip/hip_bf16.h>
#include <stddef.h>

#define BB 32
#define NN 1024
#define HH 128

using f32x4 = __attribute__((ext_vector_type(4))) float;
using f16x8 = __attribute__((ext_vector_type(8))) _Float16;
using f16x4 = __attribute__((ext_vector_type(4))) _Float16;
using s16x8 = __attribute__((ext_vector_type(8))) short;
using u16x4 = __attribute__((ext_vector_type(4))) unsigned short;
using u16x8 = __attribute__((ext_vector_type(8))) unsigned short;
typedef unsigned short ushort;

#define AS1 __attribute__((address_space(1)))
#define AS3 __attribute__((address_space(3)))
#define LOG2E 1.44269504f

static __device__ inline ushort f2bf(float f) {
    __hip_bfloat16 h = __float2bfloat16(f);   // RNE
    return __builtin_bit_cast(ushort, h);
}

// W^T in fp16, [p][n][k] = W_p[k][n]; p: 0=q, 1=k, 2=v.
__device__ _Float16 g_WT[3 * 128 * 128];

// ---------------- W transpose + cast to fp16 (3 blocks; LDS padded to 129) ----
__global__ __launch_bounds__(256) void wtrans_kernel(const float* __restrict__ Wq,
                                                     const float* __restrict__ Wk,
                                                     const float* __restrict__ Wv) {
    __shared__ float wl[128 * 129];
    const float* W = (blockIdx.x == 0) ? Wq : (blockIdx.x == 1) ? Wk : Wv;
    _Float16* dst = g_WT + blockIdx.x * 16384;
    const int tid = threadIdx.x;
    for (int i = tid; i < 4096; i += 256) {
        int row = i >> 5, c = i & 31;
        *(f32x4*)&wl[row * 129 + c * 4] = ((const f32x4*)W)[i];
    }
    __syncthreads();
    for (int s = 0; s < 8; ++s) {
        int ch = tid + s * 256;
        int n = ch >> 4, kc = ch & 15;
        f16x8 v;
        #pragma unroll
        for (int j = 0; j < 8; ++j) v[j] = (_Float16)wl[(kc * 8 + j) * 129 + n];
        *(f16x8*)&dst[n * 128 + kc * 8] = v;
    }
}

// ---------------- Proj-only prep: 512 blocks, q/k/v projections --------------
__global__ __launch_bounds__(256) void prep_kernel(
    const float* __restrict__ x,
    const float* __restrict__ bq, const float* __restrict__ bk, const float* __restrict__ bv,
    _Float16* __restrict__ qo, _Float16* __restrict__ ko, ushort* __restrict__ vTo)
{
    __shared__ __align__(16) _Float16 rep[4][16 * 136];
    __shared__ __align__(16) ushort vsm[128 * 72];

    const int tid = threadIdx.x;
    const int w = tid >> 6, ln = tid & 63, qd = ln >> 4, l16 = ln & 15;
    const int row0 = blockIdx.x * 64;
    const int rw = row0 + w * 16;
    const int b = row0 >> 10, n0 = row0 & 1023;

    f16x8 xa[4];
    {
        const float* xr = x + (size_t)(rw + l16) * 128;
        #pragma unroll
        for (int t = 0; t < 4; ++t) {
            f32x4 a0 = *(const f32x4*)(xr + t * 32 + qd * 8);
            f32x4 a1 = *(const f32x4*)(xr + t * 32 + qd * 8 + 4);
            #pragma unroll
            for (int j = 0; j < 4; ++j) { xa[t][j] = (_Float16)a0[j]; xa[t][4 + j] = (_Float16)a1[j]; }
        }
    }

    for (int p = 0; p < 3; ++p) {
        const _Float16* Wt = g_WT + p * 16384;
        const float* bias = (p == 0) ? bq : (p == 1) ? bk : bv;

        float bv_[8];
        #pragma unroll
        for (int hc = 0; hc < 8; ++hc) bv_[hc] = bias[hc * 16 + l16];

        f32x4 acc[8];
        #pragma unroll
        for (int hc = 0; hc < 8; ++hc) {
            acc[hc] = (f32x4)(0.0f);
            #pragma unroll
            for (int t = 0; t < 4; ++t) {
                f16x8 bf = *(const f16x8*)(Wt + (size_t)(hc * 16 + l16) * 128 + t * 32 + qd * 8);
                acc[hc] = __builtin_amdgcn_mfma_f32_16x16x32_f16(xa[t], bf, acc[hc], 0, 0, 0);
            }
        }

        if (p < 2) {
            _Float16* dst = (p == 0) ? qo : ko;
            const float scl = (p == 0) ? LOG2E : 1.0f;   // fold exp2 domain into q
            #pragma unroll
            for (int hc = 0; hc < 8; ++hc)
                #pragma unroll
                for (int r = 0; r < 4; ++r)
                    rep[w][(qd * 4 + r) * 136 + hc * 16 + l16] =
                        (_Float16)(fmaxf(acc[hc][r] + bv_[hc], 0.0f) * scl);
            #pragma unroll
            for (int s = 0; s < 4; ++s) {
                int ch = ln + s * 64;
                int rr = ch >> 4, kc = ch & 15;
                f16x8 v = *(const f16x8*)&rep[w][rr * 136 + kc * 8];
                *(f16x8*)&dst[(size_t)(rw + rr) * 128 + kc * 8] = v;
            }
        } else {
            #pragma unroll
            for (int hc = 0; hc < 8; ++hc)
                #pragma unroll
                for (int r = 0; r < 4; ++r)
                    vsm[(hc * 16 + l16) * 72 + w * 16 + qd * 4 + r] =
                        f2bf(fmaxf(acc[hc][r] + bv_[hc], 0.0f));
            __syncthreads();
            #pragma unroll
            for (int s = 0; s < 4; ++s) {
                int ch = tid + s * 256;
                int h = ch >> 3, g = ch & 7;
                u16x8 v = *(const u16x8*)&vsm[h * 72 + g * 8];
                *(u16x8*)&vTo[(size_t)b * HH * NN + (size_t)h * NN + n0 + g * 8] = v;
            }
        }
    }
}

// ---------------- Fused attention: DMA double-buffer + direct mask stream ----
// grid 512: b = id&31 (XCD pin), ig = id>>5; 64 i-rows, 512 thr = 8 waves.
// The 128MB f32 mask is streamed HERE (each element read exactly once, f32x4
// nontemporal), overlapped with the MFMA pipeline instead of a serial pack
// pass. Mask loads issue at the top of each j-tile (OLDER than the DMA batch
// in the in-order vmcnt queue, so waiting on them does not drain the staging
// loads); they are consumed after the QK MFMAs, ~400cy later.
// LDS: K 2x16KB + V 2x16KB + ps 10KB = 74KB -> 2 blocks/CU (grid = 2/CU).
__global__ __launch_bounds__(512, 4) void attn_kernel(
    const _Float16* __restrict__ q, const _Float16* __restrict__ k,
    const ushort* __restrict__ vT, const float* __restrict__ mask,
    float* __restrict__ out)
{
    __shared__ __align__(16) unsigned char smem[75776];
    // ks: buf*16384 + half*8192        (0 .. 32767)
    // vs: 32768 + buf*16384 + half*8192 (32768 .. 65535)
    // ps: 65536 + w*1280                (65536 .. 75775)
    float* mg = (float*)smem;                        // merge overlay after loop

    const int tid = threadIdx.x;
    const int w = tid >> 6, ln = tid & 63, qd = ln >> 4, l16 = ln & 15;
    const int pair = w >> 1, half = w & 1;
    const int b = blockIdx.x & 31, ig = blockIdx.x >> 5;
    const int i0 = ig * 64 + pair * 16;

    ushort* psw = (ushort*)(smem + 65536) + w * 640;

    // staging-role constants
    const int kh = (w & 3) >> 1, gb = (w & 1) * 4;   // K-half / group-base (w<4)
    const int vh = kh;                                // V-half (w>=4)
    const _Float16* kg0 = k + ((size_t)b * NN + kh * 512) * 128;
    const ushort*   vg0 = vT + (size_t)b * HH * NN + vh * 512;

    // this wave's mask row segment: i = i0+l16, j-half = half*512
    const float* mrow = mask + ((size_t)b * NN + i0 + l16) * NN + half * 512;

    // Q B-fragments (n = l16 = i, k = qd*8+j)
    f16x8 qf[4];
    {
        const _Float16* qrow = q + ((size_t)b * NN + i0 + l16) * 128;
        #pragma unroll
        for (int t = 0; t < 4; ++t)
            qf[t] = *(const f16x8*)(qrow + t * 32 + qd * 8);
    }

    f32x4 acc[8];
    #pragma unroll
    for (int hc = 0; hc < 8; ++hc) acc[hc] = (f32x4)(0.0f);
    float l_i = 0.0f;

    // ---- preload tile 0 into buf 0 ----
    if (w < 4) {
        unsigned char* ldsb = smem + kh * 8192;
        #pragma unroll
        for (int gi = 0; gi < 4; ++gi) {
            int g  = gb + gi;
            int r  = g * 4 + (ln >> 4);
            int cs = (ln & 15) ^ (r & 15);
            __builtin_amdgcn_global_load_lds(
                (const AS1 void*)(kg0 + (size_t)r * 128 + cs * 8),
                (AS3 void*)(ldsb + g * 1024 + (ln & 15) * 16),
                16, 0, 0);
        }
    } else {
        unsigned char* ldsb = smem + 32768 + vh * 8192;
        #pragma unroll
        for (int gi = 0; gi < 4; ++gi) {
            int g  = gb + gi;
            int h  = g * 16 + (ln >> 2);
            int cs = (ln & 3) ^ (h & 3);
            __builtin_amdgcn_global_load_lds(
                (const AS1 void*)(vg0 + (size_t)h * NN + cs * 8),
                (AS3 void*)(ldsb + g * 1024 + (ln & 3) * 16),
                16, 0, 0);
        }
    }
    __syncthreads();                           // tile 0 staged

    for (int jt = 0; jt < 16; ++jt) {
        const int cb = jt & 1, nb = cb ^ 1;

        // mask stream first (older than DMA batch -> their wait keeps DMA in flight)
        // j = half*512 + jt*32 + s*16 + qd*4 + r  matches s0/s1 row decomposition
        f32x4 m0 = __builtin_nontemporal_load((const f32x4*)(mrow + jt * 32 + qd * 4));
        f32x4 m1 = __builtin_nontemporal_load((const f32x4*)(mrow + jt * 32 + 16 + qd * 4));

        // ---- issue DMA for tile jt+1 into nb (completes by next barrier) ----
        if (jt < 15) {
            const int jo = (jt + 1) * 32;
            if (w < 4) {
                unsigned char* ldsb = smem + nb * 16384 + kh * 8192;
                #pragma unroll
                for (int gi = 0; gi < 4; ++gi) {
                    int g  = gb + gi;
                    int r  = g * 4 + (ln >> 4);
                    int cs = (ln & 15) ^ (r & 15);
                    __builtin_amdgcn_global_load_lds(
                        (const AS1 void*)(kg0 + (size_t)(jo + r) * 128 + cs * 8),
                        (AS3 void*)(ldsb + g * 1024 + (ln & 15) * 16),
                        16, 0, 0);
                }
            } else {
                unsigned char* ldsb = smem + 32768 + nb * 16384 + vh * 8192;
                #pragma unroll
                for (int gi = 0; gi < 4; ++gi) {
                    int g  = gb + gi;
                    int h  = g * 16 + (ln >> 2);
                    int cs = (ln & 3) ^ (h & 3);
                    __builtin_amdgcn_global_load_lds(
                        (const AS1 void*)(vg0 + (size_t)h * NN + jo + cs * 8),
                        (AS3 void*)(ldsb + g * 1024 + (ln & 3) * 16),
                        16, 0, 0);
                }
            }
        }

        // ---- compute on cb ----
        const _Float16* ksh = (const _Float16*)(smem + cb * 16384) + half * 4096;
        const ushort*   vsh = (const ushort*)(smem + 32768 + cb * 16384) + half * 4096;

        f32x4 s0 = (f32x4)(0.0f), s1 = (f32x4)(0.0f);
        #pragma unroll
        for (int t = 0; t < 4; ++t) {
            f16x8 kc = *(const f16x8*)&ksh[l16 * 128 + (((t * 4 + qd) ^ l16) * 8)];
            s0 = __builtin_amdgcn_mfma_f32_16x16x32_f16(kc, qf[t], s0, 0, 0, 0);
        }
        #pragma unroll
        for (int t = 0; t < 4; ++t) {
            f16x8 kc = *(const f16x8*)&ksh[(16 + l16) * 128 + (((t * 4 + qd) ^ l16) * 8)];
            s1 = __builtin_amdgcn_mfma_f32_16x16x32_f16(kc, qf[t], s1, 0, 0, 0);
        }

        // no-max softmax: p = exp2(s) (q pre-scaled by log2e), masked -> 0
        float p[8], rs = 0.0f;
        #pragma unroll
        for (int r = 0; r < 4; ++r) {
            float lg0 = (m0[r] != 0.0f) ? s0[r] : -__builtin_inff();
            float lg1 = (m1[r] != 0.0f) ? s1[r] : -__builtin_inff();
            p[r]     = exp2f(lg0);
            p[4 + r] = exp2f(lg1);
        }
        #pragma unroll
        for (int z = 0; z < 8; ++z) rs += p[z];
        l_i += rs;

        // P -> LDS as bf16 (wave-private; stride 40)
        u16x4 pk0, pk1;
        #pragma unroll
        for (int r = 0; r < 4; ++r) { pk0[r] = f2bf(p[r]); pk1[r] = f2bf(p[4 + r]); }
        *(u16x4*)&psw[l16 * 40 + qd * 4]      = pk0;
        *(u16x4*)&psw[l16 * 40 + 16 + qd * 4] = pk1;

        s16x8 pb = *(const s16x8*)&psw[l16 * 40 + qd * 8];
        #pragma unroll
        for (int hc = 0; hc < 8; ++hc) {
            s16x8 vf = *(const s16x8*)&vsh[(hc * 16 + l16) * 32 + ((qd ^ (l16 & 3)) * 8)];
            acc[hc] = __builtin_amdgcn_mfma_f32_16x16x32_bf16(vf, pb, acc[hc], 0, 0, 0);
        }

        __syncthreads();   // cb reads done; nb DMA drained (implicit vmcnt(0))
    }

    // reduce l across quads (j-partition within half)
    l_i += __shfl_xor(l_i, 16);
    l_i += __shfl_xor(l_i, 32);

    // ---- merge the two j-halves (overlay on smem) ----
    float* mgp = mg + pair * 2176;          // [16 i][136] per pair (4 pairs)
    float* ml  = mg + 8704;                 // [pair][16] l only
    if (half == 1) {
        #pragma unroll
        for (int hc = 0; hc < 8; ++hc)
            *(f32x4*)&mgp[l16 * 136 + hc * 16 + qd * 4] = acc[hc];
        if (qd == 0) ml[pair * 16 + l16] = l_i;
    }
    __syncthreads();
    if (half == 0) {
        float inv = 1.0f / (l_i + ml[pair * 16 + l16]);
        float* orow = out + ((size_t)b * NN + i0 + l16) * 128;
        #pragma unroll
        for (int hc = 0; hc < 8; ++hc) {
            f32x4 o1 = *(const f32x4*)&mgp[l16 * 136 + hc * 16 + qd * 4];
            f32x4 o = (acc[hc] + o1) * inv;
            *(f32x4*)&orow[hc * 16 + qd * 4] = o;
        }
    }
}

extern "C" void kernel_launch(void* const* d_in, const int* in_sizes, int n_in,
                              void* d_out, int out_size, void* d_ws, size_t ws_size,
                              hipStream_t stream) {
    const float* x    = (const float*)d_in[0];
    const float* mask = (const float*)d_in[1];
    const float* Wv   = (const float*)d_in[2];
    const float* bv   = (const float*)d_in[3];
    const float* Wk   = (const float*)d_in[4];
    const float* bk   = (const float*)d_in[5];
    const float* Wq   = (const float*)d_in[6];
    const float* bq   = (const float*)d_in[7];
    float* out = (float*)d_out;

    const size_t BNH = (size_t)BB * NN * HH;
    _Float16* ws  = (_Float16*)d_ws;
    ushort*   vTb = (ushort*)ws;              // [B][H][N] bf16   8 MB
    _Float16* kb  = ws + BNH;                 // [B][N][H] f16    8 MB
    _Float16* qb  = ws + 2 * BNH;             // [B][N][H] f16    8 MB

    wtrans_kernel<<<3, 256, 0, stream>>>(Wq, Wk, Wv);
    prep_kernel<<<512, 256, 0, stream>>>(x, bq, bk, bv, qb, kb, vTb);
    attn_kernel<<<512, 512, 0, stream>>>(qb, kb, vTb, mask, out);
}

// Round 2
// 268.962 us; speedup vs baseline: 1.0287x; 1.0287x over previous
//
#include <hip/hip_runtime.h>
#include <hip/hip_bf16.h>
#include <stddef.h>

#define BB 32
#define NN 1024
#define HH 128

using f32x4 = __attribute__((ext_vector_type(4))) float;
using f16x8 = __attribute__((ext_vector_type(8))) _Float16;
using f16x4 = __attribute__((ext_vector_type(4))) _Float16;
using s16x8 = __attribute__((ext_vector_type(8))) short;
using u16x4 = __attribute__((ext_vector_type(4))) unsigned short;
using u16x8 = __attribute__((ext_vector_type(8))) unsigned short;
typedef unsigned long long u64;
typedef unsigned short ushort;

#define AS1 __attribute__((address_space(1)))
#define AS3 __attribute__((address_space(3)))
#define LOG2E 1.44269504f

static __device__ inline ushort f2bf(float f) {
    __hip_bfloat16 h = __float2bfloat16(f);   // RNE
    return __builtin_bit_cast(ushort, h);
}

// W^T in fp16, [p][n][k] = W_p[k][n]; p: 0=q, 1=k, 2=v.
__device__ _Float16 g_WT[3 * 128 * 128];

// ---------------- W transpose + cast to fp16 (3 blocks; LDS padded to 129) ----
__global__ __launch_bounds__(256) void wtrans_kernel(const float* __restrict__ Wq,
                                                     const float* __restrict__ Wk,
                                                     const float* __restrict__ Wv) {
    __shared__ float wl[128 * 129];
    const float* W = (blockIdx.x == 0) ? Wq : (blockIdx.x == 1) ? Wk : Wv;
    _Float16* dst = g_WT + blockIdx.x * 16384;
    const int tid = threadIdx.x;
    for (int i = tid; i < 4096; i += 256) {
        int row = i >> 5, c = i & 31;
        *(f32x4*)&wl[row * 129 + c * 4] = ((const f32x4*)W)[i];
    }
    __syncthreads();
    for (int s = 0; s < 8; ++s) {
        int ch = tid + s * 256;
        int n = ch >> 4, kc = ch & 15;
        f16x8 v;
        #pragma unroll
        for (int j = 0; j < 8; ++j) v[j] = (_Float16)wl[(kc * 8 + j) * 129 + n];
        *(f16x8*)&dst[n * 128 + kc * 8] = v;
    }
}

// ---------------- Fused prep: proj (blocks 0-511) + maskpack (512-1535) ------
__global__ __launch_bounds__(256) void prep_kernel(
    const float* __restrict__ x,
    const float* __restrict__ bq, const float* __restrict__ bk, const float* __restrict__ bv,
    const float* __restrict__ mask,
    _Float16* __restrict__ qo, _Float16* __restrict__ ko, ushort* __restrict__ vTo,
    u64* __restrict__ bm)
{
    __shared__ __align__(16) _Float16 rep[4][16 * 136];
    __shared__ __align__(16) ushort vsm[128 * 72];

    if (blockIdx.x >= 512) {
        // ---- maskpack role: sequential stream, ballot pack ----
        const int wid = ((blockIdx.x - 512) * 256 + threadIdx.x) >> 6;
        const int ln = threadIdx.x & 63;
        for (int ch = wid; ch < BB * NN * NN / 256; ch += 4096) {
            f32x4 f = *(const f32x4*)(mask + (size_t)ch * 256 + ln * 4);
            u64 b0 = __ballot(f[0] != 0.0f);
            u64 b1 = __ballot(f[1] != 0.0f);
            u64 b2 = __ballot(f[2] != 0.0f);
            u64 b3 = __ballot(f[3] != 0.0f);
            if (ln == 0) {
                bm[(size_t)ch * 4 + 0] = b0;
                bm[(size_t)ch * 4 + 1] = b1;
                bm[(size_t)ch * 4 + 2] = b2;
                bm[(size_t)ch * 4 + 3] = b3;
            }
        }
        return;
    }

    // ---- proj role ----
    const int tid = threadIdx.x;
    const int w = tid >> 6, ln = tid & 63, qd = ln >> 4, l16 = ln & 15;
    const int row0 = blockIdx.x * 64;
    const int rw = row0 + w * 16;
    const int b = row0 >> 10, n0 = row0 & 1023;

    f16x8 xa[4];
    {
        const float* xr = x + (size_t)(rw + l16) * 128;
        #pragma unroll
        for (int t = 0; t < 4; ++t) {
            f32x4 a0 = *(const f32x4*)(xr + t * 32 + qd * 8);
            f32x4 a1 = *(const f32x4*)(xr + t * 32 + qd * 8 + 4);
            #pragma unroll
            for (int j = 0; j < 4; ++j) { xa[t][j] = (_Float16)a0[j]; xa[t][4 + j] = (_Float16)a1[j]; }
        }
    }

    for (int p = 0; p < 3; ++p) {
        const _Float16* Wt = g_WT + p * 16384;
        const float* bias = (p == 0) ? bq : (p == 1) ? bk : bv;

        float bv_[8];
        #pragma unroll
        for (int hc = 0; hc < 8; ++hc) bv_[hc] = bias[hc * 16 + l16];

        f32x4 acc[8];
        #pragma unroll
        for (int hc = 0; hc < 8; ++hc) {
            acc[hc] = (f32x4)(0.0f);
            #pragma unroll
            for (int t = 0; t < 4; ++t) {
                f16x8 bf = *(const f16x8*)(Wt + (size_t)(hc * 16 + l16) * 128 + t * 32 + qd * 8);
                acc[hc] = __builtin_amdgcn_mfma_f32_16x16x32_f16(xa[t], bf, acc[hc], 0, 0, 0);
            }
        }

        if (p < 2) {
            _Float16* dst = (p == 0) ? qo : ko;
            const float scl = (p == 0) ? LOG2E : 1.0f;   // fold exp2 domain into q
            #pragma unroll
            for (int hc = 0; hc < 8; ++hc)
                #pragma unroll
                for (int r = 0; r < 4; ++r)
                    rep[w][(qd * 4 + r) * 136 + hc * 16 + l16] =
                        (_Float16)(fmaxf(acc[hc][r] + bv_[hc], 0.0f) * scl);
            #pragma unroll
            for (int s = 0; s < 4; ++s) {
                int ch = ln + s * 64;
                int rr = ch >> 4, kc = ch & 15;
                f16x8 v = *(const f16x8*)&rep[w][rr * 136 + kc * 8];
                *(f16x8*)&dst[(size_t)(rw + rr) * 128 + kc * 8] = v;
            }
        } else {
            #pragma unroll
            for (int hc = 0; hc < 8; ++hc)
                #pragma unroll
                for (int r = 0; r < 4; ++r)
                    vsm[(hc * 16 + l16) * 72 + w * 16 + qd * 4 + r] =
                        f2bf(fmaxf(acc[hc][r] + bv_[hc], 0.0f));
            __syncthreads();
            #pragma unroll
            for (int s = 0; s < 4; ++s) {
                int ch = tid + s * 256;
                int h = ch >> 3, g = ch & 7;
                u16x8 v = *(const u16x8*)&vsm[h * 72 + g * 8];
                *(u16x8*)&vTo[(size_t)b * HH * NN + (size_t)h * NN + n0 + g * 8] = v;
            }
        }
    }
}

// ---------------- Fused attention: DOUBLE-BUFFERED DMA, S^T, no-max ----------
// grid 512: b = id&31 (XCD pin), ig = id>>5; 64 i-rows, 512 thr = 8 waves.
// ONE barrier per j-tile: iter jt issues DMA for tile jt+1 into buf^1, computes
// on buf (staged last iter), then __syncthreads (orders LDS reuse AND drains
// the in-flight DMA via its implicit vmcnt(0)). DMA latency hides behind
// MFMA+softmax instead of serializing. Mask-word loads are issued BEFORE the
// DMA batch so their wait (in-order vmcnt) doesn't drain the staging queue.
// LDS: K 2x16KB + V 2x16KB + ps 10KB = 74KB -> 2 blocks/CU (grid = 2/CU).
__global__ __launch_bounds__(512, 4) void attn_kernel(
    const _Float16* __restrict__ q, const _Float16* __restrict__ k,
    const ushort* __restrict__ vT, const u64* __restrict__ bm,
    float* __restrict__ out)
{
    __shared__ __align__(16) unsigned char smem[75776];
    // ks: buf*16384 + half*8192        (0 .. 32767)
    // vs: 32768 + buf*16384 + half*8192 (32768 .. 65535)
    // ps: 65536 + w*1280                (65536 .. 75775)
    float* mg = (float*)smem;                        // merge overlay after loop

    const int tid = threadIdx.x;
    const int w = tid >> 6, ln = tid & 63, qd = ln >> 4, l16 = ln & 15;
    const int pair = w >> 1, half = w & 1;
    const int b = blockIdx.x & 31, ig = blockIdx.x >> 5;
    const int i0 = ig * 64 + pair * 16;

    ushort* psw = (ushort*)(smem + 65536) + w * 640;

    // staging-role constants
    const int kh = (w & 3) >> 1, gb = (w & 1) * 4;   // K-half / group-base (w<4)
    const int vh = kh;                                // V-half (w>=4)
    const _Float16* kg0 = k + ((size_t)b * NN + kh * 512) * 128;
    const ushort*   vg0 = vT + (size_t)b * HH * NN + vh * 512;

    // Q B-fragments (n = l16 = i, k = qd*8+j)
    f16x8 qf[4];
    {
        const _Float16* qrow = q + ((size_t)b * NN + i0 + l16) * 128;
        #pragma unroll
        for (int t = 0; t < 4; ++t)
            qf[t] = *(const f16x8*)(qrow + t * 32 + qd * 8);
    }

    f32x4 acc[8];
    #pragma unroll
    for (int hc = 0; hc < 8; ++hc) acc[hc] = (f32x4)(0.0f);
    float l_i = 0.0f;

    u64 mw[4];
    const u64* mwp = bm + ((size_t)b * NN + i0 + l16) * 16;

    // ---- preload tile 0 into buf 0 ----
    if (w < 4) {
        unsigned char* ldsb = smem + kh * 8192;
        #pragma unroll
        for (int gi = 0; gi < 4; ++gi) {
            int g  = gb + gi;
            int r  = g * 4 + (ln >> 4);
            int cs = (ln & 15) ^ (r & 15);
            __builtin_amdgcn_global_load_lds(
                (const AS1 void*)(kg0 + (size_t)r * 128 + cs * 8),
                (AS3 void*)(ldsb + g * 1024 + (ln & 15) * 16),
                16, 0, 0);
        }
    } else {
        unsigned char* ldsb = smem + 32768 + vh * 8192;
        #pragma unroll
        for (int gi = 0; gi < 4; ++gi) {
            int g  = gb + gi;
            int h  = g * 16 + (ln >> 2);
            int cs = (ln & 3) ^ (h & 3);
            __builtin_amdgcn_global_load_lds(
                (const AS1 void*)(vg0 + (size_t)h * NN + cs * 8),
                (AS3 void*)(ldsb + g * 1024 + (ln & 3) * 16),
                16, 0, 0);
        }
    }
    __syncthreads();                           // tile 0 staged

    for (int jt = 0; jt < 16; ++jt) {
        const int cb = jt & 1, nb = cb ^ 1;

        // mask words first (their wait retires before the DMA batch, no drain)
        if ((jt & 7) == 0) {
            const u64* mp = mwp + (half * 2 + (jt >> 3)) * 4;
            mw[0] = mp[0]; mw[1] = mp[1]; mw[2] = mp[2]; mw[3] = mp[3];
        }

        // ---- issue DMA for tile jt+1 into nb (completes by next barrier) ----
        if (jt < 15) {
            const int jo = (jt + 1) * 32;
            if (w < 4) {
                unsigned char* ldsb = smem + nb * 16384 + kh * 8192;
                #pragma unroll
                for (int gi = 0; gi < 4; ++gi) {
                    int g  = gb + gi;
                    int r  = g * 4 + (ln >> 4);
                    int cs = (ln & 15) ^ (r & 15);
                    __builtin_amdgcn_global_load_lds(
                        (const AS1 void*)(kg0 + (size_t)(jo + r) * 128 + cs * 8),
                        (AS3 void*)(ldsb + g * 1024 + (ln & 15) * 16),
                        16, 0, 0);
                }
            } else {
                unsigned char* ldsb = smem + 32768 + nb * 16384 + vh * 8192;
                #pragma unroll
                for (int gi = 0; gi < 4; ++gi) {
                    int g  = gb + gi;
                    int h  = g * 16 + (ln >> 2);
                    int cs = (ln & 3) ^ (h & 3);
                    __builtin_amdgcn_global_load_lds(
                        (const AS1 void*)(vg0 + (size_t)h * NN + jo + cs * 8),
                        (AS3 void*)(ldsb + g * 1024 + (ln & 3) * 16),
                        16, 0, 0);
                }
            }
        }

        // ---- compute on cb ----
        const _Float16* ksh = (const _Float16*)(smem + cb * 16384) + half * 4096;
        const ushort*   vsh = (const ushort*)(smem + 32768 + cb * 16384) + half * 4096;

        f32x4 s0 = (f32x4)(0.0f), s1 = (f32x4)(0.0f);
        #pragma unroll
        for (int t = 0; t < 4; ++t) {
            f16x8 kc = *(const f16x8*)&ksh[l16 * 128 + (((t * 4 + qd) ^ l16) * 8)];
            s0 = __builtin_amdgcn_mfma_f32_16x16x32_f16(kc, qf[t], s0, 0, 0, 0);
        }
        #pragma unroll
        for (int t = 0; t < 4; ++t) {
            f16x8 kc = *(const f16x8*)&ksh[(16 + l16) * 128 + (((t * 4 + qd) ^ l16) * 8)];
            s1 = __builtin_amdgcn_mfma_f32_16x16x32_f16(kc, qf[t], s1, 0, 0, 0);
        }

        // no-max softmax: p = exp2(s) (q pre-scaled by log2e), masked -> 0
        const int sh0 = (jt & 7) * 8 + qd, sh1 = sh0 + 4;
        float p[8], rs = 0.0f;
        #pragma unroll
        for (int r = 0; r < 4; ++r) {
            float lg0 = ((mw[r] >> sh0) & 1ull) ? s0[r] : -__builtin_inff();
            float lg1 = ((mw[r] >> sh1) & 1ull) ? s1[r] : -__builtin_inff();
            p[r]     = exp2f(lg0);
            p[4 + r] = exp2f(lg1);
        }
        #pragma unroll
        for (int z = 0; z < 8; ++z) rs += p[z];
        l_i += rs;

        // P -> LDS as bf16 (wave-private; stride 40)
        u16x4 pk0, pk1;
        #pragma unroll
        for (int r = 0; r < 4; ++r) { pk0[r] = f2bf(p[r]); pk1[r] = f2bf(p[4 + r]); }
        *(u16x4*)&psw[l16 * 40 + qd * 4]      = pk0;
        *(u16x4*)&psw[l16 * 40 + 16 + qd * 4] = pk1;

        s16x8 pb = *(const s16x8*)&psw[l16 * 40 + qd * 8];
        #pragma unroll
        for (int hc = 0; hc < 8; ++hc) {
            s16x8 vf = *(const s16x8*)&vsh[(hc * 16 + l16) * 32 + ((qd ^ (l16 & 3)) * 8)];
            acc[hc] = __builtin_amdgcn_mfma_f32_16x16x32_bf16(vf, pb, acc[hc], 0, 0, 0);
        }

        __syncthreads();   // cb reads done; nb DMA drained (implicit vmcnt(0))
    }

    // reduce l across quads (j-partition within half)
    l_i += __shfl_xor(l_i, 16);
    l_i += __shfl_xor(l_i, 32);

    // ---- merge the two j-halves (overlay on smem) ----
    float* mgp = mg + pair * 2176;          // [16 i][136] per pair (4 pairs)
    float* ml  = mg + 8704;                 // [pair][16] l only
    if (half == 1) {
        #pragma unroll
        for (int hc = 0; hc < 8; ++hc)
            *(f32x4*)&mgp[l16 * 136 + hc * 16 + qd * 4] = acc[hc];
        if (qd == 0) ml[pair * 16 + l16] = l_i;
    }
    __syncthreads();
    if (half == 0) {
        float inv = 1.0f / (l_i + ml[pair * 16 + l16]);
        float* orow = out + ((size_t)b * NN + i0 + l16) * 128;
        #pragma unroll
        for (int hc = 0; hc < 8; ++hc) {
            f32x4 o1 = *(const f32x4*)&mgp[l16 * 136 + hc * 16 + qd * 4];
            f32x4 o = (acc[hc] + o1) * inv;
            *(f32x4*)&orow[hc * 16 + qd * 4] = o;
        }
    }
}

extern "C" void kernel_launch(void* const* d_in, const int* in_sizes, int n_in,
                              void* d_out, int out_size, void* d_ws, size_t ws_size,
                              hipStream_t stream) {
    const float* x    = (const float*)d_in[0];
    const float* mask = (const float*)d_in[1];
    const float* Wv   = (const float*)d_in[2];
    const float* bv   = (const float*)d_in[3];
    const float* Wk   = (const float*)d_in[4];
    const float* bk   = (const float*)d_in[5];
    const float* Wq   = (const float*)d_in[6];
    const float* bq   = (const float*)d_in[7];
    float* out = (float*)d_out;

    const size_t BNH = (size_t)BB * NN * HH;
    _Float16* ws  = (_Float16*)d_ws;
    ushort*   vTb = (ushort*)ws;              // [B][H][N] bf16   8 MB
    _Float16* kb  = ws + BNH;                 // [B][N][H] f16    8 MB
    _Float16* qb  = ws + 2 * BNH;             // [B][N][H] f16    8 MB
    u64* bm64 = (u64*)(ws + 3 * BNH);         // 4 MB bit words

    wtrans_kernel<<<3, 256, 0, stream>>>(Wq, Wk, Wv);
    prep_kernel<<<1536, 256, 0, stream>>>(x, bq, bk, bv, mask, qb, kb, vTb, bm64);
    attn_kernel<<<512, 512, 0, stream>>>(qb, kb, vTb, bm64, out);
}